// Round 5
// baseline (425.363 us; speedup 1.0000x reference)
//
#include <hip/hip_runtime.h>
#include <hip/hip_bf16.h>

typedef __attribute__((ext_vector_type(8))) short short8;
typedef __attribute__((ext_vector_type(4))) short short4v;
typedef __attribute__((ext_vector_type(4))) float f32x4;
typedef __attribute__((ext_vector_type(2))) float f32x2;
typedef unsigned short u16;

// ---- bf16 helpers (bit-level, RNE) ----
__device__ inline float b2f(u16 u) {
    unsigned int i = ((unsigned int)u) << 16;
    float f; __builtin_memcpy(&f, &i, 4); return f;
}
__device__ inline u16 f2b(float f) {
    unsigned int i; __builtin_memcpy(&i, &f, 4);
    unsigned int r = (i + 0x7FFFu + ((i >> 16) & 1u)) >> 16;
    return (u16)r;
}

// Cross-half (lane ^ 32) sum via v_permlane32_swap_b32 — pure VALU, no lgkm.
__device__ inline float xsum32(float x) {
    unsigned u; __builtin_memcpy(&u, &x, 4);
    auto r = __builtin_amdgcn_permlane32_swap(u, u, false, false);
    unsigned s0 = r[0], s1 = r[1];
    float f0, f1; __builtin_memcpy(&f0, &s0, 4); __builtin_memcpy(&f1, &s1, 4);
    return f0 + f1;
}

// Cross-sixteenth (lane ^ 16) sum. permlane16_swap is VALU; fallback shfl is
// ds_swizzle (lgkm) — acceptable only because the new scan has no ds_reads.
__device__ inline float xsum16(float x) {
#if __has_builtin(__builtin_amdgcn_permlane16_swap)
    unsigned u; __builtin_memcpy(&u, &x, 4);
    auto r = __builtin_amdgcn_permlane16_swap(u, u, false, false);
    unsigned s0 = r[0], s1 = r[1];
    float f0, f1; __builtin_memcpy(&f0, &s0, 4); __builtin_memcpy(&f1, &s1, 4);
    return f0 + f1;
#else
    return x + __shfl_xor(x, 16, 64);
#endif
}

#define GLDS(g, l) __builtin_amdgcn_global_load_lds( \
    (const __attribute__((address_space(1))) void*)(g), \
    (__attribute__((address_space(3))) void*)(l), 16, 0, 0)

// lgkm drain + counted vmcnt (keep prefetches in flight) + raw barrier.
#define KWAIT(N) asm volatile("s_waitcnt lgkmcnt(0)\n\t" \
                              "s_waitcnt vmcnt(" #N ")\n\t" \
                              "s_barrier" ::: "memory")

// ============================================================
// Phase 0: fp32 -> bf16 conversion (4 elements / thread)
// ============================================================
__global__ __launch_bounds__(256) void cvt_k(const float* __restrict__ src,
                                             u16* __restrict__ dst, int n4)
{
    const int i = blockIdx.x * blockDim.x + threadIdx.x;
    if (i < n4) {
        const f32x4 v = ((const f32x4*)src)[i];
        short4v o;
        o.x = (short)f2b(v.x); o.y = (short)f2b(v.y);
        o.z = (short)f2b(v.z); o.w = (short)f2b(v.w);
        ((short4v*)dst)[i] = o;
    }
}

// ============================================================
// Phase 0b: V0 transpose  V0T[b][j][n] = V0[b][n][j]  (fp32, 1 MB)
// ============================================================
__global__ __launch_bounds__(256) void vT_k(const float* __restrict__ V0,
                                            float* __restrict__ V0T)
{
    const int gid = blockIdx.x * 256 + threadIdx.x;   // 0..16383
    const int b = gid >> 9, j = (gid >> 6) & 7, n0 = (gid & 63) * 16;
    const float* src = V0 + (long)b * 8192 + (long)n0 * 8 + j;
    float* dst = V0T + (long)b * 8192 + (long)j * 1024 + n0;
#pragma unroll
    for (int i = 0; i < 16; i += 4) {
        f32x4 o = { src[(i + 0) * 8], src[(i + 1) * 8],
                    src[(i + 2) * 8], src[(i + 3) * 8] };
        *(f32x4*)(dst + i) = o;
    }
}

// ============================================================
// Phase 0c: Q-fold, split-K + split-D.
// Aqp[kc][b*8+r][d] = Σ_{n in kc-chunk} V0T[b][r][n] · Wq[n][d]
// R4's version was STILL latency-bound (~52 µs inferred): 256 blocks =
// 1 wave/SIMD, zero TLP. Now grid 1024 = 32b x 8kc x 4dg -> 4 blocks/CU =
// 4 waves/SIMD; thread owns ONE d-column (acc[8] scalars, tiny VGPR).
// Same n-order per (r,d) -> Aqp bit-identical to R4.
// ============================================================
__global__ __launch_bounds__(256) void foldq_k(const float* __restrict__ V0T,
                                               const float* __restrict__ Wq,
                                               float* __restrict__ Aqp)
{
    const int bid = blockIdx.x;          // 1024 = b(32) x kc(8) x dg(4)
    const int b  = bid >> 5;
    const int kc = (bid >> 2) & 7;
    const int dg = bid & 3;
    const int tid = threadIdx.x;
    const int d = dg * 256 + tid;

    __shared__ float rs[8][128];         // 4 KB: 8 V0T rows x 128 n
    {
        const int j = tid >> 5, nn = (tid & 31) * 4;
        *(f32x4*)&rs[j][nn] =
            *(const f32x4*)(V0T + (long)b * 8192 + j * 1024 + kc * 128 + nn);
    }
    __syncthreads();

    float acc[8];
#pragma unroll
    for (int r = 0; r < 8; ++r) acc[r] = 0.f;

    const float* wp = Wq + (long)(kc * 128) * 1024 + d;
#pragma unroll 4
    for (int nb = 0; nb < 32; ++nb) {    // batches of 4 n
        const float w0 = wp[0];
        const float w1 = wp[1024];
        const float w2 = wp[2048];
        const float w3 = wp[3072];
        wp += 4096;
#pragma unroll
        for (int r = 0; r < 8; ++r) {
            const f32x4 rv = *(const f32x4*)&rs[r][nb * 4];
            float a = acc[r];
            a = fmaf(rv.x, w0, a);
            a = fmaf(rv.y, w1, a);
            a = fmaf(rv.z, w2, a);
            a = fmaf(rv.w, w3, a);
            acc[r] = a;
        }
    }

#pragma unroll
    for (int r = 0; r < 8; ++r)
        Aqp[(long)kc * 262144 + (long)(b * 8 + r) * 1024 + d] = acc[r];
}

// Reduce the 8 K-chunk partials: Aq = Σ_kc Aqp[kc]
__global__ __launch_bounds__(256) void redq_k(const float* __restrict__ Aqp,
                                              float* __restrict__ Aq)
{
    const int i = blockIdx.x * 256 + threadIdx.x;   // 0..65535 (f32x4 groups)
    f32x4 s = ((const f32x4*)Aqp)[i];
#pragma unroll
    for (int kc = 1; kc < 8; ++kc) {
        const f32x4 p = ((const f32x4*)Aqp)[(long)kc * 65536 + i];
        s.x += p.x; s.y += p.y; s.z += p.z; s.w += p.w;
    }
    ((f32x4*)Aq)[i] = s;
}

// ============================================================
// Phase 1a: fused GEMM  C = X · W^T — 256x256 tile, counted-vmcnt pipeline.
// K,V only (Q folded away): X: [16384,1024] bf16; W: [2048,1024] bf16.
// ============================================================
__global__ __launch_bounds__(512) void gemm256_kv(
    const u16* __restrict__ Xbf, const u16* __restrict__ Wbf,
    u16* __restrict__ Ko, u16* __restrict__ Vo)
{
    __shared__ u16 lds[65536];   // 128 KB = 4 x 32 KB K-tile buffers

    const int bid = blockIdx.x;
    const int swz = (bid & 7) * 64 + (bid >> 3);   // bijective, 512 % 8 == 0
    const int bm = swz >> 3, bnx = swz & 7;
    const int widx = bnx >> 2;                     // 0 = K, 1 = V
    const int nbase = (bnx & 3) * 256;
    const int m0 = bm * 256;
    const u16* Wp = Wbf + (long)widx * 1048576;
    u16* O = (widx == 0) ? Ko : Vo;

    const int tid = threadIdx.x;
    const int w = tid >> 6;                // wave 0..7
    const int lane = tid & 63;
    const int wm = (w >> 2) * 128;         // 2 M-groups
    const int wn = (w & 3) * 64;           // 4 N-groups
    const int ln = lane & 15, qd = lane >> 4;

    // staging source pointers (per-lane, pre-swizzled; rule 21)
    const int q8 = lane >> 3, s8 = lane & 7;
    const int cc = s8 ^ q8;
    const u16* p0; const u16* p1; const u16* p2; const u16* p3;
    {
        auto mk = [&](int l) -> const u16* {
            const int r = l * 64 + w * 8 + q8;       // r & 7 == q8
            return (cc < 4)
                ? (Xbf + (long)(m0 + r) * 1024 + cc * 8)
                : (Wp  + (long)(nbase + r) * 1024 + (cc - 4) * 8);
        };
        p0 = mk(0); p1 = mk(1); p2 = mk(2); p3 = mk(3);
    }

    // fragment LDS byte offsets
    int aoff[8], boff[4];
#pragma unroll
    for (int mf = 0; mf < 8; ++mf) {
        const int ro = wm + mf * 16 + ln;
        aoff[mf] = ro * 128 + ((qd ^ (ro & 7)) * 16);
    }
#pragma unroll
    for (int nf = 0; nf < 4; ++nf) {
        const int rb = wn + nf * 16 + ln;
        boff[nf] = rb * 128 + (((4 + qd) ^ (rb & 7)) * 16);
    }

    f32x4 acc[8][4];
#pragma unroll
    for (int i = 0; i < 8; ++i)
#pragma unroll
        for (int j = 0; j < 4; ++j) acc[i][j] = (f32x4){0.f, 0.f, 0.f, 0.f};

    // prologue: stage K-tiles 0,1,2
#pragma unroll
    for (int tt = 0; tt < 3; ++tt) {
        char* db = (char*)lds + tt * 32768 + w * 1024;
        GLDS(p0, db);
        GLDS(p1, db + 8192);
        GLDS(p2, db + 16384);
        GLDS(p3, db + 24576);
        p0 += 32; p1 += 32; p2 += 32; p3 += 32;
    }
    KWAIT(8);   // tile 0 landed for every wave

    for (int t = 0; t < 32; ++t) {
        const char* bb = (const char*)lds + (t & 3) * 32768;
        short8 a[8], bfr[4];
#pragma unroll
        for (int mf = 0; mf < 4; ++mf) a[mf] = *(const short8*)(bb + aoff[mf]);
#pragma unroll
        for (int nf = 0; nf < 4; ++nf) bfr[nf] = *(const short8*)(bb + boff[nf]);
        if (t < 29) {
            char* db = (char*)lds + ((t + 3) & 3) * 32768 + w * 1024;
            GLDS(p0, db);
            GLDS(p1, db + 8192);
            p0 += 32; p1 += 32;
        }
        __builtin_amdgcn_s_setprio(1);
#pragma unroll
        for (int mf = 0; mf < 4; ++mf)
#pragma unroll
            for (int nf = 0; nf < 4; ++nf)
                acc[mf][nf] = __builtin_amdgcn_mfma_f32_16x16x32_bf16(
                    a[mf], bfr[nf], acc[mf][nf], 0, 0, 0);
        __builtin_amdgcn_s_setprio(0);
#pragma unroll
        for (int mf = 4; mf < 8; ++mf) a[mf] = *(const short8*)(bb + aoff[mf]);
        if (t < 29) {
            char* db = (char*)lds + ((t + 3) & 3) * 32768 + w * 1024;
            GLDS(p2, db + 16384);
            GLDS(p3, db + 24576);
            p2 += 32; p3 += 32;
        }
        __builtin_amdgcn_s_setprio(1);
#pragma unroll
        for (int mf = 4; mf < 8; ++mf)
#pragma unroll
            for (int nf = 0; nf < 4; ++nf)
                acc[mf][nf] = __builtin_amdgcn_mfma_f32_16x16x32_bf16(
                    a[mf], bfr[nf], acc[mf][nf], 0, 0, 0);
        __builtin_amdgcn_s_setprio(0);
        if (t < 29)       KWAIT(8);
        else if (t == 29) KWAIT(4);
        else if (t == 30) KWAIT(0);
    }

    // epilogue: C/D layout col=lane&15, row=qd*4+reg (verified m89/m91)
#pragma unroll
    for (int mf = 0; mf < 8; ++mf) {
#pragma unroll
        for (int nf = 0; nf < 4; ++nf) {
            const int r0 = m0 + wm + mf * 16 + qd * 4;
            const int c  = nbase + wn + nf * 16 + ln;
#pragma unroll
            for (int r = 0; r < 4; ++r)
                O[(long)(r0 + r) * 1024 + c] = f2b(acc[mf][nf][r]);
        }
    }
}

// ============================================================
// Phase 1c: per-row scalars, 4 t's per block.
//   S[b][t][0..7]  = 0.5 * Vtk_u * rn      (prescaled for W=2U form)
//   S[b][t][8..15] = 2.0 * k_r_u * rn
//   S[b][t][16..23]= 0.5 * Vtq   (via Aq-rows · x-rows, Q never built)
// ============================================================
__global__ __launch_bounds__(256) void scal_k(
    const u16* __restrict__ K, const u16* __restrict__ X,
    const float* __restrict__ V0T, const float* __restrict__ Wkr,
    const float* __restrict__ Aq, float* __restrict__ S)
{
    const int b  = blockIdx.x & 31;
    const int t0 = (blockIdx.x >> 5) * 4;
    const int tid = threadIdx.x;
    const int j = tid & 7, c = tid >> 3;      // c: 0..31
    const int n0 = c * 32;

    f32x4 vv[8], ww[8], aqv[8];
    {
        const f32x4* vp = (const f32x4*)(V0T + (long)b * 8192 + (long)j * 1024 + n0);
        const f32x4* wp = (const f32x4*)(Wkr + (long)j * 1024 + n0);
        const f32x4* ap = (const f32x4*)(Aq + (long)(b * 8 + j) * 1024 + n0);
#pragma unroll
        for (int i = 0; i < 8; i++) { vv[i] = vp[i]; ww[i] = wp[i]; aqv[i] = ap[i]; }
    }

    float avk[4], akr[4], avq[4], ass[4];
#pragma unroll
    for (int dt = 0; dt < 4; dt++) { avk[dt] = akr[dt] = avq[dt] = ass[dt] = 0.f; }

#pragma unroll
    for (int dt = 0; dt < 4; dt++) {
        const long m = (long)(t0 + dt) * 32 + b;
        const short8* kp = (const short8*)(K + m * 1024 + n0);
        const short8* xp = (const short8*)(X + m * 1024 + n0);
#pragma unroll
        for (int i = 0; i < 4; i++) {
            const short8 kb = kp[i], xb = xp[i];
#pragma unroll
            for (int e = 0; e < 8; e++) {
                const int idx = i * 8 + e;
                const float kv = b2f((u16)kb[e]);
                const float xv = b2f((u16)xb[e]);
                const float vj = vv[idx >> 2][idx & 3];
                const float wj = ww[idx >> 2][idx & 3];
                const float aj = aqv[idx >> 2][idx & 3];
                avk[dt] = fmaf(vj, kv, avk[dt]);
                akr[dt] = fmaf(wj, kv, akr[dt]);
                avq[dt] = fmaf(aj, xv, avq[dt]);
                ass[dt] = fmaf(kv, kv, ass[dt]);
            }
        }
    }

    __shared__ float red[4][4][3][8];   // [wave][dt][v][j]
    __shared__ float ssr[4][4];         // [wave][dt]
    const int wave = tid >> 6, lane = tid & 63;
#pragma unroll
    for (int dt = 0; dt < 4; dt++) {
        float a = avk[dt], k2 = akr[dt], q = avq[dt], s = ass[dt];
#pragma unroll
        for (int off = 8; off < 64; off <<= 1) {
            a  += __shfl_xor(a,  off, 64);
            k2 += __shfl_xor(k2, off, 64);
            q  += __shfl_xor(q,  off, 64);
            s  += __shfl_xor(s,  off, 64);
        }
        if (lane < 8) {
            red[wave][dt][0][lane] = a;
            red[wave][dt][1][lane] = k2;
            red[wave][dt][2][lane] = q;
        }
        if (lane == 0) ssr[wave][dt] = s;
    }
    __syncthreads();
    if (tid < 128) {
        const int dt = tid >> 5, rr = tid & 31;
        if (rr < 24) {
            const int v = rr >> 3, jj = rr & 7;
            float s = red[0][dt][v][jj] + red[1][dt][v][jj] +
                      red[2][dt][v][jj] + red[3][dt][v][jj];
            if (v != 2) {
                const float n2 = ssr[0][dt] + ssr[1][dt] + ssr[2][dt] + ssr[3][dt];
                const float inv = 1.0f / (sqrtf(n2) + 1e-6f);
                s *= (v == 0) ? (0.5f * inv) : (2.0f * inv);
            } else {
                s *= 0.5f;
            }
            S[((long)b * 512 + t0 + dt) * 32 + v * 8 + jj] = s;
        }
    }
}

// ============================================================
// Phase 2: the scan, r-split x4 — lane = (n, r-quarter), U[2] per lane.
// 512 blocks x 256 thr = 2048 waves -> 8 waves/CU = 2/SIMD (2x the TLP of
// the old r-split x2). ZERO LDS: S read directly from global (2 MB,
// L2-resident) through an 8-deep rotating register pipeline (static
// indices; ~8 steps of slack >= HBM latency). Cross-quarter sums via
// permlane16_swap + permlane32_swap (pure VALU). The `ret` reduction tree
// is bit-identical to the r-split x2 version -> U recurrence unchanged;
// only the Sq readout reassociates (~1 ulp, output-only).
// ============================================================
__global__ __launch_bounds__(256) void scan_k(
    const u16* __restrict__ Vbuf, const float* __restrict__ S,
    const float* __restrict__ U0, float* __restrict__ outp,
    float* __restrict__ Ufin)
{
    const int b = blockIdx.x >> 4;
    const int chunk = blockIdx.x & 15;          // n-chunk of 64
    const int wave = threadIdx.x >> 6, lane = threadIdx.x & 63;
    const int rq = lane >> 4;                   // r-quarter 0..3 (j = rq*2, rq*2+1)
    const int nl = lane & 15;
    const int n = chunk * 64 + wave * 16 + nl;
    const int so = rq * 2;

    float U[2];   // holds W = 2*U for its j-pair
    {
        const float* u0 = U0 + ((long)b * 1024 + n) * 8 + so;
        U[0] = 2.0f * u0[0];
        U[1] = 2.0f * u0[1];
    }

    const u16* vp0 = Vbuf + (long)b * 1024 + n;
    u16 vnx[16];
#pragma unroll
    for (int i = 0; i < 16; i++) vnx[i] = vp0[(long)i * 32768];

    // 8-deep rotating S register pipeline, straight from global (no LDS)
    const float* Sp = S + (long)b * 16384 + so;   // + t*32 + v*8
    f32x2 sb[8][3];
#pragma unroll
    for (int s = 0; s < 8; ++s)
#pragma unroll
        for (int v = 0; v < 3; ++v)
            sb[s][v] = *(const f32x2*)(Sp + s * 32 + v * 8);

    float* op = outp + (long)b * 1024 + n;

    for (int t0 = 0; t0 < 512; t0 += 16) {
        float vcur[16];
#pragma unroll
        for (int i = 0; i < 16; i++) vcur[i] = b2f(vnx[i]);
        const int tn = (t0 + 16 < 512) ? (t0 + 16) : t0;
#pragma unroll
        for (int i = 0; i < 16; i++) vnx[i] = vp0[(long)(tn + i) * 32768];

#pragma unroll
        for (int i = 0; i < 16; i++) {
            const int t = t0 + i;
            const int slot = i & 7;
            const f32x2 a = sb[slot][0], Kk = sb[slot][1], Qq = sb[slot][2];

            // retrieved: per-quarter fma pair + 16/32 butterfly
            // (bit-identical tree to the old r-split x2 version)
            const float pr = fmaf(U[0], a.x, U[1] * a.y);
            const float ret = xsum32(xsum16(pr));
            const float delta = vcur[i] - ret;

            const float x0 = fmaf(delta, Kk.x, U[0]);          // = 2x
            const float x1 = fmaf(delta, Kk.y, U[1]);
            const float e0 = __expf(x0);                       // exp(2x)
            const float e1 = __expf(x1);
            const float u0n = fmaf(-4.0f, __builtin_amdgcn_rcpf(e0 + 1.0f), 2.0f);
            const float u1n = fmaf(-4.0f, __builtin_amdgcn_rcpf(e1 + 1.0f), 2.0f);
            U[0] = u0n; U[1] = u1n;

            const float sqp = fmaf(u1n, Qq.y, u0n * Qq.x);

            // prefetch S row t+8 into the slot just consumed
            const int tf = (t + 8 < 512) ? (t + 8) : 511;
#pragma unroll
            for (int v = 0; v < 3; ++v)
                sb[slot][v] = *(const f32x2*)(Sp + tf * 32 + v * 8);

            const float Sq = xsum32(xsum16(sqp));
            const float sg = __builtin_amdgcn_rcpf(1.0f + __expf(-Sq));
            const float o = Sq * Sq * sg;  // Sq * silu(Sq)
            if (rq == 0) op[(long)t * 32768] = o;
        }
    }

    // U_final: undo W=2U scaling; lane stores its j-pair (8B)
    *(f32x2*)(Ufin + ((long)b * 1024 + n) * 8 + so) =
        (f32x2){0.5f * U[0], 0.5f * U[1]};
}

// ============================================================
// V output = V0 (unchanged); 16B-wide fp32 copy (262144 floats)
// ============================================================
__global__ __launch_bounds__(256) void vcopy_k(const float* __restrict__ src,
                                               float* __restrict__ dst)
{
    const int i = blockIdx.x * blockDim.x + threadIdx.x;  // 0..65535
    ((f32x4*)dst)[i] = ((const f32x4*)src)[i];
}

// ============================================================
extern "C" void kernel_launch(void* const* d_in, const int* in_sizes, int n_in,
                              void* d_out, int out_size, void* d_ws, size_t ws_size,
                              hipStream_t stream)
{
    const float* x   = (const float*)d_in[0];   // [512,32,1024]
    const float* Wk  = (const float*)d_in[1];   // [1024,1024]
    const float* Wv  = (const float*)d_in[2];
    const float* Wq  = (const float*)d_in[3];
    const float* Wkr = (const float*)d_in[4];   // [8,1024]
    const float* U0  = (const float*)d_in[5];   // [32,1024,8]
    const float* V0  = (const float*)d_in[6];   // [32,1024,8]
    float* out = (float*)d_out;                 // output(16777216) + U_final(262144) + V(262144)

    char* ws = (char*)d_ws;
    u16*   Xbf = (u16*)(ws);                    // 33,554,432 B
    u16*   Wbf = (u16*)(ws + 33554432);         //  4,194,304 B used (Wk|Wv stacked)
    u16*   Kb  = (u16*)(ws + 39845888);         // 33,554,432 B
    u16*   Vb  = (u16*)(ws + 73400320);         // 33,554,432 B
    float* Aq  = (float*)(ws + 106954752);      //  1,048,576 B  (256 x 1024 f32)
    float* Aqp = (float*)(ws + 108003328);      //  8,388,608 B  (8 x 256 x 1024 f32)
    float* Sc  = (float*)(ws + 140509184);      //  2,097,152 B  (32 x 512 x 32 f32)
    float* V0T = (float*)(ws + 142606336);      //  1,048,576 B  (32 x 8 x 1024 f32)

    cvt_k<<<16384, 256, 0, stream>>>(x,  Xbf,               4194304);
    cvt_k<<<1024,  256, 0, stream>>>(Wk, Wbf,                262144);
    cvt_k<<<1024,  256, 0, stream>>>(Wv, Wbf + 1048576,      262144);
    vT_k <<<64,    256, 0, stream>>>(V0, V0T);
    foldq_k<<<1024, 256, 0, stream>>>(V0T, Wq, Aqp);
    redq_k <<<256, 256, 0, stream>>>(Aqp, Aq);

    gemm256_kv<<<512, 512, 0, stream>>>(Xbf, Wbf, Kb, Vb);
    scal_k  <<<4096, 256, 0, stream>>>(Kb, Xbf, V0T, Wkr, Aq, Sc);
    scan_k  <<<512, 256, 0, stream>>>(Vb, Sc, U0, out, out + 16777216);
    vcopy_k <<<256, 256, 0, stream>>>(V0, out + 17039360);
}